// Round 6
// baseline (753.886 us; speedup 1.0000x reference)
//
#include <hip/hip_runtime.h>
#include <hip/hip_bf16.h>
#include <stdint.h>

#define D_MODEL 1024
#define N_HEADS 16
#define D_KH    64
#define BATCH   4
#define SEQ     2048
#define M_TOTAL (BATCH * SEQ)   // 8192

typedef unsigned short u16;
typedef short  bf16x8 __attribute__((ext_vector_type(8)));
typedef float  f32x4  __attribute__((ext_vector_type(4)));

__device__ __forceinline__ float bf2f(u16 u) {
    union { uint32_t i; float f; } c; c.i = ((uint32_t)u) << 16; return c.f;
}
__device__ __forceinline__ u16 f2bf(float f) {          // RNE (epilogues)
    union { float f; uint32_t i; } c; c.f = f;
    uint32_t r = (c.i + 0x7FFFu + ((c.i >> 16) & 1u)) >> 16;
    return (u16)r;
}
__device__ __forceinline__ u16 f2bf_fast(float f) {     // round-half-up (P tiles)
    union { float f; uint32_t i; } c; c.f = f;
    return (u16)((c.i + 0x8000u) >> 16);
}
__device__ __forceinline__ float sane(float v) {
    return (v == v && v > -1e30f && v < 1e30f) ? v : 0.f;
}
__device__ __forceinline__ float loadf(const void* base, size_t idx, int isbf) {
    return isbf ? bf2f(((const u16*)base)[idx]) : ((const float*)base)[idx];
}

// ---------------------------------------------------------------------------
// Runtime dtype detector (1 = bf16 inputs, 0 = fp32 inputs).
// ---------------------------------------------------------------------------
__global__ void detect_dtype(const uint32_t* __restrict__ w, int* __restrict__ flag) {
    uint32_t word = w[threadIdx.x & 63];
    uint32_t e = (word >> 7) & 0xFFu;
    unsigned long long m = __ballot(e >= 64u && e <= 160u);
    if (threadIdx.x == 0) *flag = (__popcll(m) >= 48) ? 1 : 0;
}

// ---------------------------------------------------------------------------
// X fp32 -> bf16 (skipped entirely in bf16 mode).
// ---------------------------------------------------------------------------
__global__ __launch_bounds__(256) void convert_x(
    const void* __restrict__ x, u16* __restrict__ dst, const int* __restrict__ flag)
{
    if (*flag) return;
    size_t i = ((size_t)blockIdx.x * 256 + threadIdx.x) * 8;
    const float* f = (const float*)x + i;
    float4 a = *(const float4*)f;
    float4 b = *(const float4*)(f + 4);
    union { ushort4 v; u16 s[4]; } lo, hi;
    lo.s[0] = f2bf(a.x); lo.s[1] = f2bf(a.y); lo.s[2] = f2bf(a.z); lo.s[3] = f2bf(a.w);
    hi.s[0] = f2bf(b.x); hi.s[1] = f2bf(b.y); hi.s[2] = f2bf(b.z); hi.s[3] = f2bf(b.w);
    *(ushort4*)&dst[i]     = lo.v;
    *(ushort4*)&dst[i + 4] = hi.v;
}

// ---------------------------------------------------------------------------
// W [k][n] (fp32 or bf16) -> W^T [n][k] bf16.  64x64 tiles via LDS.
// ---------------------------------------------------------------------------
__global__ __launch_bounds__(256) void transpose_w(
    const void* __restrict__ W0, const void* __restrict__ W1,
    const void* __restrict__ W2, u16* __restrict__ dst,
    const int* __restrict__ flag)
{
    const int mat = blockIdx.z;
    const void* W = (mat == 0) ? W0 : ((mat == 1) ? W1 : W2);
    const int isbf = *flag;
    const int n0 = blockIdx.x << 6, k0 = blockIdx.y << 6;
    __shared__ u16 Ts[64 * 72];
    const int t = threadIdx.x;
    const int rr = t >> 4, cc = (t & 15) << 2;

#pragma unroll
    for (int i = 0; i < 4; i++) {
        int row = rr + i * 16;
        if (isbf) {
            ushort4 v = *(const ushort4*)((const u16*)W + (size_t)(k0 + row) * D_MODEL + n0 + cc);
            *(ushort4*)&Ts[row * 72 + cc] = v;
        } else {
            float4 f = *(const float4*)((const float*)W + (size_t)(k0 + row) * D_MODEL + n0 + cc);
            Ts[row * 72 + cc + 0] = f2bf(f.x);
            Ts[row * 72 + cc + 1] = f2bf(f.y);
            Ts[row * 72 + cc + 2] = f2bf(f.z);
            Ts[row * 72 + cc + 3] = f2bf(f.w);
        }
    }
    __syncthreads();
#pragma unroll
    for (int i = 0; i < 4; i++) {
        int n = rr + i * 16;
        union { ushort4 v; u16 s[4]; } o;
        o.s[0] = Ts[(cc + 0) * 72 + n];
        o.s[1] = Ts[(cc + 1) * 72 + n];
        o.s[2] = Ts[(cc + 2) * 72 + n];
        o.s[3] = Ts[(cc + 3) * 72 + n];
        *(ushort4*)&dst[(size_t)mat * 1048576 + (size_t)(n0 + n) * D_MODEL + k0 + cc] = o.v;
    }
}

// ---------------------------------------------------------------------------
// Fused QKV GEMM: 128x128 tile, 4 waves, 4x4 acc/wave. (unchanged, passing)
// ---------------------------------------------------------------------------
__global__ __launch_bounds__(256) void qkv_gemm(
    const void* __restrict__ Xorig, const u16* __restrict__ Xbf,
    const u16* __restrict__ Wt,
    const void* __restrict__ bq, const void* __restrict__ bk, const void* __restrict__ bv,
    u16* __restrict__ Qd, u16* __restrict__ Kw, u16* __restrict__ Vt,
    const int* __restrict__ flag)
{
    const int isbf = *flag;
    const u16* Xp = isbf ? (const u16*)Xorig : Xbf;

    const int tid = threadIdx.x;
    const int wave = tid >> 6, lane = tid & 63;
    const int quad = lane >> 4, l15 = lane & 15;
    const int wr = wave >> 1, wc = wave & 1;

    const int nt  = blockIdx.x;        // 0..23
    const int mat = nt >> 3;           // 0=Q,1=K,2=V
    const int n0m = (nt & 7) << 7;
    const int m0  = blockIdx.y << 7;

    const u16* Wmat = Wt + (size_t)mat * 1048576;
    const void* bias = (mat == 0) ? bq : ((mat == 1) ? bk : bv);

    __shared__ __align__(16) u16 As[128 * 36];
    __shared__ __align__(16) u16 Bs[128 * 36];

    f32x4 acc[4][4];
#pragma unroll
    for (int i = 0; i < 4; i++)
#pragma unroll
        for (int j = 0; j < 4; j++) acc[i][j] = (f32x4){0.f, 0.f, 0.f, 0.f};

    for (int k0 = 0; k0 < D_MODEL; k0 += 32) {
#pragma unroll
        for (int i = 0; i < 2; i++) {
            int c = tid + (i << 8);
            int row = c >> 2, koff = (c & 3) << 3;
            *(uint4*)&As[row * 36 + koff] =
                *(const uint4*)&Xp[(size_t)(m0 + row) * D_MODEL + k0 + koff];
            *(uint4*)&Bs[row * 36 + koff] =
                *(const uint4*)&Wmat[(size_t)(n0m + row) * D_MODEL + k0 + koff];
        }
        __syncthreads();

        bf16x8 af[4], bf[4];
#pragma unroll
        for (int ms = 0; ms < 4; ms++)
            af[ms] = *(const bf16x8*)&As[(wr * 64 + ms * 16 + l15) * 36 + quad * 8];
#pragma unroll
        for (int ns = 0; ns < 4; ns++)
            bf[ns] = *(const bf16x8*)&Bs[(wc * 64 + ns * 16 + l15) * 36 + quad * 8];
#pragma unroll
        for (int ms = 0; ms < 4; ms++)
#pragma unroll
            for (int ns = 0; ns < 4; ns++)
                acc[ms][ns] = __builtin_amdgcn_mfma_f32_16x16x32_bf16(af[ms], bf[ns], acc[ms][ns], 0, 0, 0);
        __syncthreads();
    }

#pragma unroll
    for (int ns = 0; ns < 4; ns++) {
        int c = n0m + wc * 64 + ns * 16 + l15;
        float bv_ = loadf(bias, c, isbf);
        int h = c >> 6, d = c & 63;
#pragma unroll
        for (int ms = 0; ms < 4; ms++) {
            int rbase = m0 + wr * 64 + ms * 16 + quad * 4;
            int b = rbase >> 11;
            int sbase = rbase & 2047;
            int bh = b * N_HEADS + h;
            if (mat == 2) {
                union { ushort4 v; u16 s[4]; } o;
#pragma unroll
                for (int r = 0; r < 4; r++) o.s[r] = f2bf(sane(acc[ms][ns][r] + bv_));
                *(ushort4*)&Vt[((size_t)bh * D_KH + d) * SEQ + sbase] = o.v;
            } else {
                u16* Out = (mat == 0) ? Qd : Kw;
#pragma unroll
                for (int r = 0; r < 4; r++)
                    Out[((size_t)bh * SEQ + sbase + r) * D_KH + d] =
                        f2bf(sane(acc[ms][ns][r] + bv_));
            }
        }
    }
}

// ---------------------------------------------------------------------------
// Causal flash attention v6: fine-grained balanced packing.
//   - 64-row q tiles, ONE tile per block, 2 waves (128 thr), 32 rows/wave
//     (R1-grade per-wave efficiency; wave-iter total unchanged).
//   - 2048 blocks, ALL co-resident: 8 blocks/CU (4 waves/SIMD at <=128 VGPR,
//     8 KB LDS/block) -> 16 waves/CU = 2x R1's TLP.
//   - Balance-interleaved qt order per bh: 31,0,30,1,29,2,28,3|27,4,...
//     every aligned chunk of 8 blocks sums to exactly 132 k-iters ->
//     per-CU load is uniform under chunked assignment; longest-first helps
//     greedy schedulers otherwise (fixes R5's 12% time-avg occupancy).
//   - XCD swizzle kept (R5: FETCH 147 -> 24.6 MB, K/V L2-resident).
//   - Body: transposed scores, 2-shfl softmax, defer-max, swizzled P LDS,
//     V early-issue, K ping-pong (tail-safe for odd trip counts).
// ---------------------------------------------------------------------------
__global__ __launch_bounds__(128, 4) void attn_kernel(
    const u16* __restrict__ Qd, const u16* __restrict__ Kw,
    const u16* __restrict__ Vt, u16* __restrict__ Aw)
{
    const int tid = threadIdx.x;
    const int wave = tid >> 6, lane = tid & 63;
    const int quad = lane >> 4, l15 = lane & 15;

    // wg -> (xcd, bh, qt64) with balance interleave.
    const int wg    = blockIdx.x;                 // 0..2047
    const int xcd   = wg & 7;
    const int local = wg >> 3;                    // 0..255
    const int bhl   = local >> 5;                 // 0..7
    const int t     = local & 31;                 // 0..31
    const int qt64  = (t & 1) ? (t >> 1) : (31 - (t >> 1));  // 31,0,30,1,...
    const int bh    = (xcd << 3) | bhl;           // 0..63
    const int b  = bh >> 4, h = bh & 15;

    const u16* Qb = Qd + (size_t)bh * SEQ * D_KH;
    const u16* Kb = Kw + (size_t)bh * SEQ * D_KH;
    const u16* Vb = Vt + (size_t)bh * D_KH * SEQ;

    __shared__ __align__(16) u16 Ps[2][32 * 64];  // wave-private, swizzled
    char* Pw = (char*)Ps[wave];

    const float CEXP = 0.18033688011112042f;      // log2(e) / sqrt(64)

    const int qrow0 = qt64 * 64 + wave * 32;      // this wave's first q row

    // Q fragments (B-operand of QK): lane l15 = q-within-16, d = quad*8..
    bf16x8 qf[2][2];
#pragma unroll
    for (int qs = 0; qs < 2; qs++) {
        const u16* qrow = Qb + (size_t)(qrow0 + qs * 16 + l15) * D_KH + quad * 8;
        qf[qs][0] = *(const bf16x8*)(qrow);
        qf[qs][1] = *(const bf16x8*)(qrow + 32);
    }

    float mi[2], li[2];
    f32x4 od[4][2];                               // O^T: [d-tile][q-half]
    mi[0] = mi[1] = -1e9f; li[0] = li[1] = 0.f;
#pragma unroll
    for (int db = 0; db < 4; db++)
#pragma unroll
        for (int qs = 0; qs < 2; qs++) od[db][qs] = (f32x4){0.f, 0.f, 0.f, 0.f};

    const int ktn = qt64 + 1;                     // trip count (1..32)

    auto kload = [&](bf16x8 (&kf)[4][2], int k0) {
#pragma unroll
        for (int nb = 0; nb < 4; nb++) {
            const u16* kr = Kb + (size_t)(k0 + nb * 16 + l15) * D_KH + quad * 8;
            kf[nb][0] = *(const bf16x8*)(kr);
            kf[nb][1] = *(const bf16x8*)(kr + 32);
        }
    };

    auto body = [&](bf16x8 (&kcur)[4][2], bf16x8 (&knxt)[4][2], int kt, bool pf) {
        const int k0 = kt << 6;

        // ---- V^T fragments: issue first, consumed after softmax ----
        bf16x8 vb[4][2];
#pragma unroll
        for (int db = 0; db < 4; db++) {
            const u16* vr = Vb + (size_t)(db * 16 + l15) * SEQ + k0 + quad * 8;
            vb[db][0] = *(const bf16x8*)(vr);
            vb[db][1] = *(const bf16x8*)(vr + 32);
        }

        // ---- S^T = K Q^T : st[nb][qs], row=key(quad*4+r), col=q(l15) ----
        f32x4 st[4][2];
        __builtin_amdgcn_s_setprio(1);
#pragma unroll
        for (int nb = 0; nb < 4; nb++)
#pragma unroll
            for (int qs = 0; qs < 2; qs++) {
                f32x4 tt = (f32x4){0.f, 0.f, 0.f, 0.f};
                tt = __builtin_amdgcn_mfma_f32_16x16x32_bf16(kcur[nb][0], qf[qs][0], tt, 0, 0, 0);
                tt = __builtin_amdgcn_mfma_f32_16x16x32_bf16(kcur[nb][1], qf[qs][1], tt, 0, 0, 0);
                st[nb][qs] = tt;
            }
        __builtin_amdgcn_s_setprio(0);

        // ---- prefetch next K tile: latency hides under softmax+PV ----
        if (pf) kload(knxt, k0 + 64);

        // ---- causal mask: only the diagonal k-tile needs it ----
        if (kt == qt64) {
#pragma unroll
            for (int qs = 0; qs < 2; qs++) {
                const int q = qrow0 + qs * 16 + l15;
#pragma unroll
                for (int nb = 0; nb < 4; nb++) {
                    const int kb0 = k0 + nb * 16 + quad * 4;
#pragma unroll
                    for (int r = 0; r < 4; r++)
                        if (kb0 + r > q) st[nb][qs][r] = -1e9f;
                }
            }
        }

        // ---- online softmax: in-lane tree + 2 shfl, defer-max ----
#pragma unroll
        for (int qs = 0; qs < 2; qs++) {
            float a0 = fmaxf(fmaxf(st[0][qs][0], st[0][qs][1]), fmaxf(st[0][qs][2], st[0][qs][3]));
            float a1 = fmaxf(fmaxf(st[1][qs][0], st[1][qs][1]), fmaxf(st[1][qs][2], st[1][qs][3]));
            float a2 = fmaxf(fmaxf(st[2][qs][0], st[2][qs][1]), fmaxf(st[2][qs][2], st[2][qs][3]));
            float a3 = fmaxf(fmaxf(st[3][qs][0], st[3][qs][1]), fmaxf(st[3][qs][2], st[3][qs][3]));
            float pmax = fmaxf(fmaxf(a0, a1), fmaxf(a2, a3));
            pmax = fmaxf(pmax, __shfl_xor(pmax, 16, 64));
            pmax = fmaxf(pmax, __shfl_xor(pmax, 32, 64));
            if (__any(pmax > mi[qs] + 8.0f)) {            // rescale (rare)
                float mnew  = fmaxf(mi[qs], pmax);
                float alpha = exp2f((mi[qs] - mnew) * CEXP);
                mi[qs] = mnew;
                li[qs] *= alpha;
#pragma unroll
                for (int db = 0; db < 4; db++) {
                    od[db][qs][0] *= alpha; od[db][qs][1] *= alpha;
                    od[db][qs][2] *= alpha; od[db][qs][3] *= alpha;
                }
            }
            const float mc = mi[qs] * CEXP;
            float srow = 0.f;
#pragma unroll
            for (int nb = 0; nb < 4; nb++) {
                union { ushort4 v; u16 s[4]; } pk;
#pragma unroll
                for (int r = 0; r < 4; r++) {
                    float pf2 = exp2f(fmaf(st[nb][qs][r], CEXP, -mc));
                    srow += pf2;
                    pk.s[r] = f2bf_fast(pf2);
                }
                // swizzled write: 8B chunk (4nb+quad) ^ ((l15&7)<<1)
                const int sw = (4 * nb + quad) ^ ((l15 & 7) << 1);
                *(ushort4*)(Pw + (qs * 16 + l15) * 128 + sw * 8) = pk.v;
            }
            srow += __shfl_xor(srow, 16, 64);
            srow += __shfl_xor(srow, 32, 64);
            li[qs] += srow;
        }

        // ---- P fragments (B-operand): swizzled 16B chunk reads ----
        bf16x8 pa[2][2];
#pragma unroll
        for (int qs = 0; qs < 2; qs++)
#pragma unroll
            for (int j = 0; j < 2; j++) {
                const int mw = (4 * j + quad) ^ (l15 & 7);
                pa[qs][j] = *(const bf16x8*)(Pw + (qs * 16 + l15) * 128 + mw * 16);
            }

        // ---- O^T += V^T P ----
        __builtin_amdgcn_s_setprio(1);
#pragma unroll
        for (int db = 0; db < 4; db++)
#pragma unroll
            for (int qs = 0; qs < 2; qs++) {
                od[db][qs] = __builtin_amdgcn_mfma_f32_16x16x32_bf16(vb[db][0], pa[qs][0], od[db][qs], 0, 0, 0);
                od[db][qs] = __builtin_amdgcn_mfma_f32_16x16x32_bf16(vb[db][1], pa[qs][1], od[db][qs], 0, 0, 0);
            }
        __builtin_amdgcn_s_setprio(0);
    };

    bf16x8 kfA[4][2], kfB[4][2];
    kload(kfA, 0);
    int kt = 0;
    for (; kt + 2 <= ktn; kt += 2) {              // 2x unrolled ping-pong
        body(kfA, kfB, kt,     true);
        body(kfB, kfA, kt + 1, kt + 2 < ktn);
    }
    if (kt < ktn) body(kfA, kfB, kt, false);      // odd-trip tail

    // ---- epilogue: O^T scatter, Aw[b*2048+q][h*64+d] bf16 ----
#pragma unroll
    for (int qs = 0; qs < 2; qs++) {
        const int q = qrow0 + qs * 16 + l15;
        const float inv = 1.0f / fmaxf(li[qs], 1e-30f);
        u16* orow = Aw + (size_t)(b * SEQ + q) * D_MODEL + h * D_KH;
#pragma unroll
        for (int db = 0; db < 4; db++)
#pragma unroll
            for (int r = 0; r < 4; r++)
                orow[db * 16 + quad * 4 + r] = f2bf(sane(od[db][qs][r] * inv));
    }
}

// ---------------------------------------------------------------------------
// Output projection: Aw[8192,1024] @ Wo (via Wo^T bf16) + bo -> d_out
// ---------------------------------------------------------------------------
__global__ __launch_bounds__(256) void out_gemm(
    const u16* __restrict__ A, const u16* __restrict__ Wot,
    const void* __restrict__ bias, void* __restrict__ Out,
    const int* __restrict__ flag)
{
    const int isbf = *flag;
    const int tid = threadIdx.x;
    const int wave = tid >> 6, lane = tid & 63;
    const int quad = lane >> 4, l15 = lane & 15;
    const int wr = wave >> 1, wc = wave & 1;

    const int n0 = blockIdx.x << 7;
    const int m0 = blockIdx.y << 7;

    __shared__ __align__(16) u16 As[128 * 36];
    __shared__ __align__(16) u16 Bs[128 * 36];

    f32x4 acc[4][4];
#pragma unroll
    for (int i = 0; i < 4; i++)
#pragma unroll
        for (int j = 0; j < 4; j++) acc[i][j] = (f32x4){0.f, 0.f, 0.f, 0.f};

    for (int k0 = 0; k0 < D_MODEL; k0 += 32) {
#pragma unroll
        for (int i = 0; i < 2; i++) {
            int c = tid + (i << 8);
            int row = c >> 2, koff = (c & 3) << 3;
            *(uint4*)&As[row * 36 + koff] =
                *(const uint4*)&A[(size_t)(m0 + row) * D_MODEL + k0 + koff];
            *(uint4*)&Bs[row * 36 + koff] =
                *(const uint4*)&Wot[(size_t)(n0 + row) * D_MODEL + k0 + koff];
        }
        __syncthreads();

        bf16x8 af[4], bf[4];
#pragma unroll
        for (int ms = 0; ms < 4; ms++)
            af[ms] = *(const bf16x8*)&As[(wr * 64 + ms * 16 + l15) * 36 + quad * 8];
#pragma unroll
        for (int ns = 0; ns < 4; ns++)
            bf[ns] = *(const bf16x8*)&Bs[(wc * 64 + ns * 16 + l15) * 36 + quad * 8];
#pragma unroll
        for (int ms = 0; ms < 4; ms++)
#pragma unroll
            for (int ns = 0; ns < 4; ns++)
                acc[ms][ns] = __builtin_amdgcn_mfma_f32_16x16x32_bf16(af[ms], bf[ns], acc[ms][ns], 0, 0, 0);
        __syncthreads();
    }

#pragma unroll
    for (int ns = 0; ns < 4; ns++) {
        int col = n0 + wc * 64 + ns * 16 + l15;
        float bv_ = loadf(bias, col, isbf);
#pragma unroll
        for (int ms = 0; ms < 4; ms++) {
#pragma unroll
            for (int r = 0; r < 4; r++) {
                int row = m0 + wr * 64 + ms * 16 + quad * 4 + r;
                float v = sane(acc[ms][ns][r] + bv_);
                size_t idx = (size_t)row * D_MODEL + col;
                if (isbf) ((u16*)Out)[idx] = f2bf(v);
                else      ((float*)Out)[idx] = v;
            }
        }
    }
}

__global__ void zero_out_kernel(void* out, int n, const int* flag) {
    int i = blockIdx.x * 256 + threadIdx.x;
    if (i < n) {
        if (*flag) ((u16*)out)[i] = 0;
        else       ((float*)out)[i] = 0.f;
    }
}

// ---------------------------------------------------------------------------
extern "C" void kernel_launch(void* const* d_in, const int* in_sizes, int n_in,
                              void* d_out, int out_size, void* d_ws, size_t ws_size,
                              hipStream_t stream)
{
    const void* x  = d_in[0];
    const void* Wq = d_in[1];
    const void* bq = d_in[2];
    const void* Wk = d_in[3];
    const void* bk = d_in[4];
    const void* Wv = d_in[5];
    const void* bv = d_in[6];
    const void* Wo = d_in[7];
    const void* bo = d_in[8];

    const size_t NELT = (size_t)M_TOTAL * D_MODEL;
    const size_t HDR  = 4096;
    const size_t NEED = HDR + 3 * NELT * sizeof(u16);    // 48 MB (proven fit)

    int* flag = (int*)d_ws;
    detect_dtype<<<1, 64, 0, stream>>>((const uint32_t*)Wq, flag);

    if (ws_size < NEED) {
        zero_out_kernel<<<(out_size + 255) / 256, 256, 0, stream>>>(d_out, out_size, flag);
        return;
    }

    u16* base = (u16*)((char*)d_ws + HDR);
    u16* Kw      = base;                 // [bh][s][d]      16 MB
    u16* Vt      = base + NELT;          // [bh][d][s]      16 MB
    u16* Wo_t    = Vt;                   // 2 MB, written AFTER attn (Vt dead)
    u16* Wqkv_t  = base + 2 * NELT;      // 6 MB  (prepass w, ph1 r)
    u16* Aw      = base + 2 * NELT;      // 16 MB (ph2 w, ph3 r)
    u16* Qd      = (u16*)d_out;          // Q scratch
    u16* Xbf     = (u16*)d_out + NELT;   // fp32 mode only

    convert_x<<<dim3(M_TOTAL * D_MODEL / (8 * 256)), 256, 0, stream>>>(x, Xbf, flag);
    transpose_w<<<dim3(16, 16, 3), 256, 0, stream>>>(Wq, Wk, Wv, Wqkv_t, flag);

    qkv_gemm<<<dim3(24, 64), 256, 0, stream>>>(x, Xbf, Wqkv_t, bq, bk, bv,
                                               Qd, Kw, Vt, flag);
    attn_kernel<<<dim3(2048), 128, 0, stream>>>(Qd, Kw, Vt, Aw);
    transpose_w<<<dim3(16, 16, 1), 256, 0, stream>>>(Wo, Wo, Wo, Wo_t, flag);
    out_gemm<<<dim3(8, 64), 256, 0, stream>>>(Aw, Wo_t, bo, d_out, flag);
}

// Round 10
// 361.915 us; speedup vs baseline: 2.0830x; 2.0830x over previous
//
#include <hip/hip_runtime.h>
#include <hip/hip_bf16.h>
#include <stdint.h>

#define D_MODEL 1024
#define N_HEADS 16
#define D_KH    64
#define BATCH   4
#define SEQ     2048
#define M_TOTAL (BATCH * SEQ)   // 8192

typedef unsigned short u16;
typedef short  bf16x8 __attribute__((ext_vector_type(8)));
typedef float  f32x4  __attribute__((ext_vector_type(4)));

__device__ __forceinline__ float bf2f(u16 u) {
    union { uint32_t i; float f; } c; c.i = ((uint32_t)u) << 16; return c.f;
}
__device__ __forceinline__ u16 f2bf(float f) {          // RNE (epilogues)
    union { float f; uint32_t i; } c; c.f = f;
    uint32_t r = (c.i + 0x7FFFu + ((c.i >> 16) & 1u)) >> 16;
    return (u16)r;
}
__device__ __forceinline__ u16 f2bf_fast(float f) {     // round-half-up (P tiles)
    union { float f; uint32_t i; } c; c.f = f;
    return (u16)((c.i + 0x8000u) >> 16);
}
__device__ __forceinline__ float sane(float v) {
    return (v == v && v > -1e30f && v < 1e30f) ? v : 0.f;
}
__device__ __forceinline__ float loadf(const void* base, size_t idx, int isbf) {
    return isbf ? bf2f(((const u16*)base)[idx]) : ((const float*)base)[idx];
}

// ---------------------------------------------------------------------------
// Runtime dtype detector (1 = bf16 inputs, 0 = fp32 inputs).
// ---------------------------------------------------------------------------
__global__ void detect_dtype(const uint32_t* __restrict__ w, int* __restrict__ flag) {
    uint32_t word = w[threadIdx.x & 63];
    uint32_t e = (word >> 7) & 0xFFu;
    unsigned long long m = __ballot(e >= 64u && e <= 160u);
    if (threadIdx.x == 0) *flag = (__popcll(m) >= 48) ? 1 : 0;
}

// ---------------------------------------------------------------------------
// X fp32 -> bf16 (skipped entirely in bf16 mode).
// ---------------------------------------------------------------------------
__global__ __launch_bounds__(256) void convert_x(
    const void* __restrict__ x, u16* __restrict__ dst, const int* __restrict__ flag)
{
    if (*flag) return;
    size_t i = ((size_t)blockIdx.x * 256 + threadIdx.x) * 8;
    const float* f = (const float*)x + i;
    float4 a = *(const float4*)f;
    float4 b = *(const float4*)(f + 4);
    union { ushort4 v; u16 s[4]; } lo, hi;
    lo.s[0] = f2bf(a.x); lo.s[1] = f2bf(a.y); lo.s[2] = f2bf(a.z); lo.s[3] = f2bf(a.w);
    hi.s[0] = f2bf(b.x); hi.s[1] = f2bf(b.y); hi.s[2] = f2bf(b.z); hi.s[3] = f2bf(b.w);
    *(ushort4*)&dst[i]     = lo.v;
    *(ushort4*)&dst[i + 4] = hi.v;
}

// ---------------------------------------------------------------------------
// W [k][n] (fp32 or bf16) -> W^T [n][k] bf16.  64x64 tiles via LDS.
// ---------------------------------------------------------------------------
__global__ __launch_bounds__(256) void transpose_w(
    const void* __restrict__ W0, const void* __restrict__ W1,
    const void* __restrict__ W2, u16* __restrict__ dst,
    const int* __restrict__ flag)
{
    const int mat = blockIdx.z;
    const void* W = (mat == 0) ? W0 : ((mat == 1) ? W1 : W2);
    const int isbf = *flag;
    const int n0 = blockIdx.x << 6, k0 = blockIdx.y << 6;
    __shared__ u16 Ts[64 * 72];
    const int t = threadIdx.x;
    const int rr = t >> 4, cc = (t & 15) << 2;

#pragma unroll
    for (int i = 0; i < 4; i++) {
        int row = rr + i * 16;
        if (isbf) {
            ushort4 v = *(const ushort4*)((const u16*)W + (size_t)(k0 + row) * D_MODEL + n0 + cc);
            *(ushort4*)&Ts[row * 72 + cc] = v;
        } else {
            float4 f = *(const float4*)((const float*)W + (size_t)(k0 + row) * D_MODEL + n0 + cc);
            Ts[row * 72 + cc + 0] = f2bf(f.x);
            Ts[row * 72 + cc + 1] = f2bf(f.y);
            Ts[row * 72 + cc + 2] = f2bf(f.z);
            Ts[row * 72 + cc + 3] = f2bf(f.w);
        }
    }
    __syncthreads();
#pragma unroll
    for (int i = 0; i < 4; i++) {
        int n = rr + i * 16;
        union { ushort4 v; u16 s[4]; } o;
        o.s[0] = Ts[(cc + 0) * 72 + n];
        o.s[1] = Ts[(cc + 1) * 72 + n];
        o.s[2] = Ts[(cc + 2) * 72 + n];
        o.s[3] = Ts[(cc + 3) * 72 + n];
        *(ushort4*)&dst[(size_t)mat * 1048576 + (size_t)(n0 + n) * D_MODEL + k0 + cc] = o.v;
    }
}

// ---------------------------------------------------------------------------
// Fused QKV GEMM: 128x128 tile, 4 waves, 4x4 acc/wave. (unchanged, passing)
// ---------------------------------------------------------------------------
__global__ __launch_bounds__(256) void qkv_gemm(
    const void* __restrict__ Xorig, const u16* __restrict__ Xbf,
    const u16* __restrict__ Wt,
    const void* __restrict__ bq, const void* __restrict__ bk, const void* __restrict__ bv,
    u16* __restrict__ Qd, u16* __restrict__ Kw, u16* __restrict__ Vt,
    const int* __restrict__ flag)
{
    const int isbf = *flag;
    const u16* Xp = isbf ? (const u16*)Xorig : Xbf;

    const int tid = threadIdx.x;
    const int wave = tid >> 6, lane = tid & 63;
    const int quad = lane >> 4, l15 = lane & 15;
    const int wr = wave >> 1, wc = wave & 1;

    const int nt  = blockIdx.x;        // 0..23
    const int mat = nt >> 3;           // 0=Q,1=K,2=V
    const int n0m = (nt & 7) << 7;
    const int m0  = blockIdx.y << 7;

    const u16* Wmat = Wt + (size_t)mat * 1048576;
    const void* bias = (mat == 0) ? bq : ((mat == 1) ? bk : bv);

    __shared__ __align__(16) u16 As[128 * 36];
    __shared__ __align__(16) u16 Bs[128 * 36];

    f32x4 acc[4][4];
#pragma unroll
    for (int i = 0; i < 4; i++)
#pragma unroll
        for (int j = 0; j < 4; j++) acc[i][j] = (f32x4){0.f, 0.f, 0.f, 0.f};

    for (int k0 = 0; k0 < D_MODEL; k0 += 32) {
#pragma unroll
        for (int i = 0; i < 2; i++) {
            int c = tid + (i << 8);
            int row = c >> 2, koff = (c & 3) << 3;
            *(uint4*)&As[row * 36 + koff] =
                *(const uint4*)&Xp[(size_t)(m0 + row) * D_MODEL + k0 + koff];
            *(uint4*)&Bs[row * 36 + koff] =
                *(const uint4*)&Wmat[(size_t)(n0m + row) * D_MODEL + k0 + koff];
        }
        __syncthreads();

        bf16x8 af[4], bf[4];
#pragma unroll
        for (int ms = 0; ms < 4; ms++)
            af[ms] = *(const bf16x8*)&As[(wr * 64 + ms * 16 + l15) * 36 + quad * 8];
#pragma unroll
        for (int ns = 0; ns < 4; ns++)
            bf[ns] = *(const bf16x8*)&Bs[(wc * 64 + ns * 16 + l15) * 36 + quad * 8];
#pragma unroll
        for (int ms = 0; ms < 4; ms++)
#pragma unroll
            for (int ns = 0; ns < 4; ns++)
                acc[ms][ns] = __builtin_amdgcn_mfma_f32_16x16x32_bf16(af[ms], bf[ns], acc[ms][ns], 0, 0, 0);
        __syncthreads();
    }

#pragma unroll
    for (int ns = 0; ns < 4; ns++) {
        int c = n0m + wc * 64 + ns * 16 + l15;
        float bv_ = loadf(bias, c, isbf);
        int h = c >> 6, d = c & 63;
#pragma unroll
        for (int ms = 0; ms < 4; ms++) {
            int rbase = m0 + wr * 64 + ms * 16 + quad * 4;
            int b = rbase >> 11;
            int sbase = rbase & 2047;
            int bh = b * N_HEADS + h;
            if (mat == 2) {
                union { ushort4 v; u16 s[4]; } o;
#pragma unroll
                for (int r = 0; r < 4; r++) o.s[r] = f2bf(sane(acc[ms][ns][r] + bv_));
                *(ushort4*)&Vt[((size_t)bh * D_KH + d) * SEQ + sbase] = o.v;
            } else {
                u16* Out = (mat == 0) ? Qd : Kw;
#pragma unroll
                for (int r = 0; r < 4; r++)
                    Out[((size_t)bh * SEQ + sbase + r) * D_KH + d] =
                        f2bf(sane(acc[ms][ns][r] + bv_));
            }
        }
    }
}

// ---------------------------------------------------------------------------
// Causal flash attention v9: EXACT R1 body (proven 140.7 us, ran cleanly).
// Only changes vs R1:
//   1. Grid transposed to (64, 8): blockIdx.x = bh, blockIdx.y = p.
//      With x-fastest round-robin dispatch, xcd = linear%8 = bh%8, so each
//      XCD owns bh in {xcd, xcd+8, ...} = 8 heads = 4 MB K/V = one L2
//      (R5-proven: FETCH 147 -> 24.6 MB). No new index math in-kernel.
//   2. P LDS round-trip uses the R5-proven XOR swizzle (write 8B chunk
//      (4nb+quad)^((l15&7)<<1), read 16B chunk (4j+quad)^(l15&7)) instead
//      of R1's 72-stride pad (8-way read conflict).
// Balanced pairing (p, 15-p) kept: every block exactly 34 k-iters.
// launch_bounds(256,2): only spill-free regime for this body.
// ---------------------------------------------------------------------------
__global__ __launch_bounds__(256, 2) void attn_kernel(
    const u16* __restrict__ Qd, const u16* __restrict__ Kw,
    const u16* __restrict__ Vt, u16* __restrict__ Aw)
{
    const int tid = threadIdx.x;
    const int wave = tid >> 6, lane = tid & 63;
    const int quad = lane >> 4, l15 = lane & 15;

    const int bh = blockIdx.x;     // 0..63  (bh%8 = XCD under round-robin)
    const int p  = blockIdx.y;     // 0..7 pair index
    const int b  = bh >> 4, h = bh & 15;

    const u16* Qb = Qd + (size_t)bh * SEQ * D_KH;
    const u16* Kb = Kw + (size_t)bh * SEQ * D_KH;
    const u16* Vb = Vt + (size_t)bh * D_KH * SEQ;

    __shared__ __align__(16) u16 Ps[4][32 * 64];   // wave-private, swizzled
    char* Pw = (char*)Ps[wave];

    const float CEXP = 0.18033688011112042f;       // log2(e) / sqrt(64)

    for (int ph = 0; ph < 2; ph++) {
        const int qt = ph ? (15 - p) : p;          // 128-row q tile index
        const int qrow0 = qt * 128 + wave * 32;    // this wave's first q row

        // Q fragments (B-operand of QK): lane l15 = q-within-16, d = quad*8..
        bf16x8 qf[2][2];
#pragma unroll
        for (int qs = 0; qs < 2; qs++) {
            const u16* qrow = Qb + (size_t)(qrow0 + qs * 16 + l15) * D_KH + quad * 8;
            qf[qs][0] = *(const bf16x8*)(qrow);
            qf[qs][1] = *(const bf16x8*)(qrow + 32);
        }

        float mi[2], li[2];
        f32x4 od[4][2];                            // O^T: [d-tile][q-half]
        mi[0] = mi[1] = -1e9f; li[0] = li[1] = 0.f;
#pragma unroll
        for (int db = 0; db < 4; db++)
#pragma unroll
            for (int qs = 0; qs < 2; qs++) od[db][qs] = (f32x4){0.f, 0.f, 0.f, 0.f};

        const int ktmax = 2 * qt + 1;              // trip count 2qt+2 is even

        auto kload = [&](bf16x8 (&kf)[4][2], int k0) {
#pragma unroll
            for (int nb = 0; nb < 4; nb++) {
                const u16* kr = Kb + (size_t)(k0 + nb * 16 + l15) * D_KH + quad * 8;
                kf[nb][0] = *(const bf16x8*)(kr);
                kf[nb][1] = *(const bf16x8*)(kr + 32);
            }
        };

        auto body = [&](bf16x8 (&kcur)[4][2], bf16x8 (&knxt)[4][2], int kt) {
            const int k0 = kt << 6;

            // ---- V^T fragments: issue first, consumed after softmax ----
            bf16x8 vb[4][2];
#pragma unroll
            for (int db = 0; db < 4; db++) {
                const u16* vr = Vb + (size_t)(db * 16 + l15) * SEQ + k0 + quad * 8;
                vb[db][0] = *(const bf16x8*)(vr);
                vb[db][1] = *(const bf16x8*)(vr + 32);
            }

            // ---- S^T = K Q^T : st[nb][qs], row=key(quad*4+r), col=q(l15) ----
            f32x4 st[4][2];
            __builtin_amdgcn_s_setprio(1);
#pragma unroll
            for (int nb = 0; nb < 4; nb++)
#pragma unroll
                for (int qs = 0; qs < 2; qs++) {
                    f32x4 t = (f32x4){0.f, 0.f, 0.f, 0.f};
                    t = __builtin_amdgcn_mfma_f32_16x16x32_bf16(kcur[nb][0], qf[qs][0], t, 0, 0, 0);
                    t = __builtin_amdgcn_mfma_f32_16x16x32_bf16(kcur[nb][1], qf[qs][1], t, 0, 0, 0);
                    st[nb][qs] = t;
                }
            __builtin_amdgcn_s_setprio(0);

            // ---- prefetch next K tile: latency hides under softmax+PV ----
            if (kt < ktmax) kload(knxt, k0 + 64);

            // ---- causal mask: only the two diagonal tiles need it ----
            if (kt >= 2 * qt) {
#pragma unroll
                for (int qs = 0; qs < 2; qs++) {
                    const int q = qrow0 + qs * 16 + l15;
#pragma unroll
                    for (int nb = 0; nb < 4; nb++) {
                        const int kb0 = k0 + nb * 16 + quad * 4;
#pragma unroll
                        for (int r = 0; r < 4; r++)
                            if (kb0 + r > q) st[nb][qs][r] = -1e9f;
                    }
                }
            }

            // ---- online softmax: in-lane tree + 2 shfl, defer-max ----
#pragma unroll
            for (int qs = 0; qs < 2; qs++) {
                float a0 = fmaxf(fmaxf(st[0][qs][0], st[0][qs][1]), fmaxf(st[0][qs][2], st[0][qs][3]));
                float a1 = fmaxf(fmaxf(st[1][qs][0], st[1][qs][1]), fmaxf(st[1][qs][2], st[1][qs][3]));
                float a2 = fmaxf(fmaxf(st[2][qs][0], st[2][qs][1]), fmaxf(st[2][qs][2], st[2][qs][3]));
                float a3 = fmaxf(fmaxf(st[3][qs][0], st[3][qs][1]), fmaxf(st[3][qs][2], st[3][qs][3]));
                float pmax = fmaxf(fmaxf(a0, a1), fmaxf(a2, a3));
                pmax = fmaxf(pmax, __shfl_xor(pmax, 16, 64));
                pmax = fmaxf(pmax, __shfl_xor(pmax, 32, 64));
                if (__any(pmax > mi[qs] + 8.0f)) {             // rescale (rare)
                    float mnew  = fmaxf(mi[qs], pmax);
                    float alpha = exp2f((mi[qs] - mnew) * CEXP);
                    mi[qs] = mnew;
                    li[qs] *= alpha;
#pragma unroll
                    for (int db = 0; db < 4; db++) {
                        od[db][qs][0] *= alpha; od[db][qs][1] *= alpha;
                        od[db][qs][2] *= alpha; od[db][qs][3] *= alpha;
                    }
                }
                const float mc = mi[qs] * CEXP;
                float srow = 0.f;
#pragma unroll
                for (int nb = 0; nb < 4; nb++) {
                    union { ushort4 v; u16 s[4]; } pk;
#pragma unroll
                    for (int r = 0; r < 4; r++) {
                        float pf = exp2f(fmaf(st[nb][qs][r], CEXP, -mc));
                        srow += pf;
                        pk.s[r] = f2bf_fast(pf);
                    }
                    // swizzled write: 8B chunk (4nb+quad) ^ ((l15&7)<<1)
                    const int sw = (4 * nb + quad) ^ ((l15 & 7) << 1);
                    *(ushort4*)(Pw + (qs * 16 + l15) * 128 + sw * 8) = pk.v;
                }
                srow += __shfl_xor(srow, 16, 64);
                srow += __shfl_xor(srow, 32, 64);
                li[qs] += srow;
            }

            // ---- P fragments (B-operand): swizzled 16B chunk reads ----
            bf16x8 pa[2][2];
#pragma unroll
            for (int qs = 0; qs < 2; qs++)
#pragma unroll
                for (int j = 0; j < 2; j++) {
                    const int mw = (4 * j + quad) ^ (l15 & 7);
                    pa[qs][j] = *(const bf16x8*)(Pw + (qs * 16 + l15) * 128 + mw * 16);
                }

            // ---- O^T += V^T P ----
            __builtin_amdgcn_s_setprio(1);
#pragma unroll
            for (int db = 0; db < 4; db++)
#pragma unroll
                for (int qs = 0; qs < 2; qs++) {
                    od[db][qs] = __builtin_amdgcn_mfma_f32_16x16x32_bf16(vb[db][0], pa[qs][0], od[db][qs], 0, 0, 0);
                    od[db][qs] = __builtin_amdgcn_mfma_f32_16x16x32_bf16(vb[db][1], pa[qs][1], od[db][qs], 0, 0, 0);
                }
            __builtin_amdgcn_s_setprio(0);
        };

        bf16x8 kfA[4][2], kfB[4][2];
        kload(kfA, 0);
        for (int kt = 0; kt <= ktmax; kt += 2) {   // always an even trip count
            body(kfA, kfB, kt);
            body(kfB, kfA, kt + 1);
        }

        // ---- epilogue: O^T scatter, Aw[b*2048+q][h*64+d] bf16 ----
#pragma unroll
        for (int qs = 0; qs < 2; qs++) {
            const int q = qrow0 + qs * 16 + l15;
            const float inv = 1.0f / fmaxf(li[qs], 1e-30f);
            u16* orow = Aw + (size_t)(b * SEQ + q) * D_MODEL + h * D_KH;
#pragma unroll
            for (int db = 0; db < 4; db++)
#pragma unroll
                for (int r = 0; r < 4; r++)
                    orow[db * 16 + quad * 4 + r] = f2bf(sane(od[db][qs][r] * inv));
        }
    }
}

// ---------------------------------------------------------------------------
// Output projection: Aw[8192,1024] @ Wo (via Wo^T bf16) + bo -> d_out
// ---------------------------------------------------------------------------
__global__ __launch_bounds__(256) void out_gemm(
    const u16* __restrict__ A, const u16* __restrict__ Wot,
    const void* __restrict__ bias, void* __restrict__ Out,
    const int* __restrict__ flag)
{
    const int isbf = *flag;
    const int tid = threadIdx.x;
    const int wave = tid >> 6, lane = tid & 63;
    const int quad = lane >> 4, l15 = lane & 15;
    const int wr = wave >> 1, wc = wave & 1;

    const int n0 = blockIdx.x << 7;
    const int m0 = blockIdx.y << 7;

    __shared__ __align__(16) u16 As[128 * 36];
    __shared__ __align__(16) u16 Bs[128 * 36];

    f32x4 acc[4][4];
#pragma unroll
    for (int i = 0; i < 4; i++)
#pragma unroll
        for (int j = 0; j < 4; j++) acc[i][j] = (f32x4){0.f, 0.f, 0.f, 0.f};

    for (int k0 = 0; k0 < D_MODEL; k0 += 32) {
#pragma unroll
        for (int i = 0; i < 2; i++) {
            int c = tid + (i << 8);
            int row = c >> 2, koff = (c & 3) << 3;
            *(uint4*)&As[row * 36 + koff] =
                *(const uint4*)&A[(size_t)(m0 + row) * D_MODEL + k0 + koff];
            *(uint4*)&Bs[row * 36 + koff] =
                *(const uint4*)&Wot[(size_t)(n0 + row) * D_MODEL + k0 + koff];
        }
        __syncthreads();

        bf16x8 af[4], bf[4];
#pragma unroll
        for (int ms = 0; ms < 4; ms++)
            af[ms] = *(const bf16x8*)&As[(wr * 64 + ms * 16 + l15) * 36 + quad * 8];
#pragma unroll
        for (int ns = 0; ns < 4; ns++)
            bf[ns] = *(const bf16x8*)&Bs[(wc * 64 + ns * 16 + l15) * 36 + quad * 8];
#pragma unroll
        for (int ms = 0; ms < 4; ms++)
#pragma unroll
            for (int ns = 0; ns < 4; ns++)
                acc[ms][ns] = __builtin_amdgcn_mfma_f32_16x16x32_bf16(af[ms], bf[ns], acc[ms][ns], 0, 0, 0);
        __syncthreads();
    }

#pragma unroll
    for (int ns = 0; ns < 4; ns++) {
        int col = n0 + wc * 64 + ns * 16 + l15;
        float bv_ = loadf(bias, col, isbf);
#pragma unroll
        for (int ms = 0; ms < 4; ms++) {
#pragma unroll
            for (int r = 0; r < 4; r++) {
                int row = m0 + wr * 64 + ms * 16 + quad * 4 + r;
                float v = sane(acc[ms][ns][r] + bv_);
                size_t idx = (size_t)row * D_MODEL + col;
                if (isbf) ((u16*)Out)[idx] = f2bf(v);
                else      ((float*)Out)[idx] = v;
            }
        }
    }
}

__global__ void zero_out_kernel(void* out, int n, const int* flag) {
    int i = blockIdx.x * 256 + threadIdx.x;
    if (i < n) {
        if (*flag) ((u16*)out)[i] = 0;
        else       ((float*)out)[i] = 0.f;
    }
}

// ---------------------------------------------------------------------------
extern "C" void kernel_launch(void* const* d_in, const int* in_sizes, int n_in,
                              void* d_out, int out_size, void* d_ws, size_t ws_size,
                              hipStream_t stream)
{
    const void* x  = d_in[0];
    const void* Wq = d_in[1];
    const void* bq = d_in[2];
    const void* Wk = d_in[3];
    const void* bk = d_in[4];
    const void* Wv = d_in[5];
    const void* bv = d_in[6];
    const void* Wo = d_in[7];
    const void* bo = d_in[8];

    const size_t NELT = (size_t)M_TOTAL * D_MODEL;
    const size_t HDR  = 4096;
    const size_t NEED = HDR + 3 * NELT * sizeof(u16);    // 48 MB (proven fit)

    int* flag = (int*)d_ws;
    detect_dtype<<<1, 64, 0, stream>>>((const uint32_t*)Wq, flag);

    if (ws_size < NEED) {
        zero_out_kernel<<<(out_size + 255) / 256, 256, 0, stream>>>(d_out, out_size, flag);
        return;
    }

    u16* base = (u16*)((char*)d_ws + HDR);
    u16* Kw      = base;                 // [bh][s][d]      16 MB
    u16* Vt      = base + NELT;          // [bh][d][s]      16 MB
    u16* Wo_t    = Vt;                   // 2 MB, written AFTER attn (Vt dead)
    u16* Wqkv_t  = base + 2 * NELT;      // 6 MB  (prepass w, ph1 r)
    u16* Aw      = base + 2 * NELT;      // 16 MB (ph2 w, ph3 r)
    u16* Qd      = (u16*)d_out;          // Q scratch
    u16* Xbf     = (u16*)d_out + NELT;   // fp32 mode only

    convert_x<<<dim3(M_TOTAL * D_MODEL / (8 * 256)), 256, 0, stream>>>(x, Xbf, flag);
    transpose_w<<<dim3(16, 16, 3), 256, 0, stream>>>(Wq, Wk, Wv, Wqkv_t, flag);

    qkv_gemm<<<dim3(24, 64), 256, 0, stream>>>(x, Xbf, Wqkv_t, bq, bk, bv,
                                               Qd, Kw, Vt, flag);
    attn_kernel<<<dim3(64, 8), 256, 0, stream>>>(Qd, Kw, Vt, Aw);
    transpose_w<<<dim3(16, 16, 1), 256, 0, stream>>>(Wo, Wo, Wo, Wo_t, flag);
    out_gemm<<<dim3(8, 64), 256, 0, stream>>>(Aw, Wo_t, bo, d_out, flag);
}